// Round 1
// baseline (1218.139 us; speedup 1.0000x reference)
//
#include <hip/hip_runtime.h>

// Problem: GCNConv(100k nodes, 1M edges, D=128) + two heads (128->64).
// ws layout (floats): deg[n] | dinv[n] | h[n*128] | agg[n*128]  (~103 MB)

#define BLOCK 256

__global__ __launch_bounds__(BLOCK) void k_degree(const int* __restrict__ dst, int E,
                                                  float* __restrict__ deg) {
    int i = blockIdx.x * blockDim.x + threadIdx.x;
    int stride = gridDim.x * blockDim.x;
    for (int e = i; e < E; e += stride) {
        unsafeAtomicAdd(&deg[dst[e]], 1.0f);
    }
}

__global__ __launch_bounds__(BLOCK) void k_dinv(const float* __restrict__ deg,
                                                float* __restrict__ dinv, int n) {
    int i = blockIdx.x * blockDim.x + threadIdx.x;
    if (i < n) dinv[i] = rsqrtf(deg[i] + 1.0f);  // +1 = self-loop
}

// h = x @ W   (n x 128) * (128 x 128), W staged in LDS (64 KB)
__global__ __launch_bounds__(BLOCK) void k_gemm_xw(const float* __restrict__ x,
                                                   const float* __restrict__ W,
                                                   float* __restrict__ h, int n) {
    __shared__ float Ws[128 * 128];
    const float4* W4 = (const float4*)W;
    float4* Ws4 = (float4*)Ws;
    for (int i = threadIdx.x; i < 128 * 32; i += BLOCK) Ws4[i] = W4[i];
    __syncthreads();

    int row = blockIdx.x * 64 + (threadIdx.x >> 2);
    if (row >= n) return;
    int cg = threadIdx.x & 3;  // column group: 32 cols each

    float acc[32];
#pragma unroll
    for (int j = 0; j < 32; j++) acc[j] = 0.f;

    const float4* xrow4 = (const float4*)(x + (size_t)row * 128);
    for (int k4 = 0; k4 < 32; k4++) {
        float4 xv = xrow4[k4];
#pragma unroll
        for (int kk = 0; kk < 4; kk++) {
            float xs = (&xv.x)[kk];
            int k = k4 * 4 + kk;
            const float4* wrow = (const float4*)(Ws + k * 128 + cg * 32);
#pragma unroll
            for (int j4 = 0; j4 < 8; j4++) {
                float4 wv = wrow[j4];
                acc[j4 * 4 + 0] += xs * wv.x;
                acc[j4 * 4 + 1] += xs * wv.y;
                acc[j4 * 4 + 2] += xs * wv.z;
                acc[j4 * 4 + 3] += xs * wv.w;
            }
        }
    }
    float4* hout = (float4*)(h + (size_t)row * 128 + cg * 32);
#pragma unroll
    for (int j4 = 0; j4 < 8; j4++)
        hout[j4] = make_float4(acc[j4 * 4 + 0], acc[j4 * 4 + 1],
                               acc[j4 * 4 + 2], acc[j4 * 4 + 3]);
}

// one wave per edge: agg[dst] += dinv[src]*dinv[dst]*h[src]
__global__ __launch_bounds__(BLOCK) void k_scatter(const int* __restrict__ src,
                                                   const int* __restrict__ dst, int E,
                                                   const float* __restrict__ dinv,
                                                   const float* __restrict__ h,
                                                   float* __restrict__ agg) {
    int wave = (blockIdx.x * blockDim.x + threadIdx.x) >> 6;
    int lane = threadIdx.x & 63;
    int nwaves = (gridDim.x * blockDim.x) >> 6;
    for (int e = wave; e < E; e += nwaves) {
        int s = src[e];
        int d = dst[e];
        float norm = dinv[s] * dinv[d];
        float2 v = ((const float2*)(h + (size_t)s * 128))[lane];
        float* arow = agg + (size_t)d * 128 + lane * 2;
        unsafeAtomicAdd(arow + 0, v.x * norm);
        unsafeAtomicAdd(arow + 1, v.y * norm);
    }
}

// out = [ (agg + h/deg + b_gcn) @ [W_high | W_low] + [b_high | b_low] ]
__global__ __launch_bounds__(BLOCK) void k_final(const float* __restrict__ agg,
                                                 const float* __restrict__ h,
                                                 const float* __restrict__ deg,
                                                 const float* __restrict__ bg,
                                                 const float* __restrict__ Wh,
                                                 const float* __restrict__ bh,
                                                 const float* __restrict__ Wl,
                                                 const float* __restrict__ bl,
                                                 float* __restrict__ out, int n) {
    __shared__ float Wc[128 * 128];  // [k][c]: c<64 -> W_high, c>=64 -> W_low
    for (int i = threadIdx.x; i < 128 * 64; i += BLOCK) {
        int k = i >> 6, c = i & 63;
        Wc[k * 128 + c] = Wh[k * 64 + c];
        Wc[k * 128 + 64 + c] = Wl[k * 64 + c];
    }
    __syncthreads();

    int row = blockIdx.x * 64 + (threadIdx.x >> 2);
    if (row >= n) return;
    int cg = threadIdx.x & 3;
    float inv = 1.0f / (deg[row] + 1.0f);  // self-loop norm = dinv^2

    float acc[32];
#pragma unroll
    for (int j = 0; j < 32; j++) {
        int c = cg * 32 + j;
        acc[j] = (c < 64) ? bh[c] : bl[c - 64];
    }

    const float4* a4 = (const float4*)(agg + (size_t)row * 128);
    const float4* h4 = (const float4*)(h + (size_t)row * 128);
    const float4* b4 = (const float4*)bg;
    for (int k4 = 0; k4 < 32; k4++) {
        float4 av = a4[k4];
        float4 hv = h4[k4];
        float4 bv = b4[k4];
#pragma unroll
        for (int kk = 0; kk < 4; kk++) {
            float hf = (&av.x)[kk] + (&hv.x)[kk] * inv + (&bv.x)[kk];
            int k = k4 * 4 + kk;
            const float4* wrow = (const float4*)(Wc + k * 128 + cg * 32);
#pragma unroll
            for (int j4 = 0; j4 < 8; j4++) {
                float4 wv = wrow[j4];
                acc[j4 * 4 + 0] += hf * wv.x;
                acc[j4 * 4 + 1] += hf * wv.y;
                acc[j4 * 4 + 2] += hf * wv.z;
                acc[j4 * 4 + 3] += hf * wv.w;
            }
        }
    }

    float* high = out;
    float* low = out + (size_t)n * 64;
#pragma unroll
    for (int j4 = 0; j4 < 8; j4++) {
        int c = cg * 32 + j4 * 4;
        float4 v = make_float4(acc[j4 * 4 + 0], acc[j4 * 4 + 1],
                               acc[j4 * 4 + 2], acc[j4 * 4 + 3]);
        if (c < 64)
            ((float4*)(high + (size_t)row * 64))[c >> 2] = v;
        else
            ((float4*)(low + (size_t)row * 64))[(c - 64) >> 2] = v;
    }
}

extern "C" void kernel_launch(void* const* d_in, const int* in_sizes, int n_in,
                              void* d_out, int out_size, void* d_ws, size_t ws_size,
                              hipStream_t stream) {
    const float* x  = (const float*)d_in[0];
    const int*   ei = (const int*)d_in[1];
    const float* Wg = (const float*)d_in[2];
    const float* bg = (const float*)d_in[3];
    const float* Wh = (const float*)d_in[4];
    const float* bh = (const float*)d_in[5];
    const float* Wl = (const float*)d_in[6];
    const float* bl = (const float*)d_in[7];
    float* out = (float*)d_out;

    int n = in_sizes[0] / 128;  // 100000
    int E = in_sizes[1] / 2;    // 1000000
    const int* src = ei;
    const int* dst = ei + E;

    float* ws = (float*)d_ws;
    float* deg  = ws;                      // n
    float* dinv = deg + n;                 // n
    float* h    = dinv + n;                // n*128
    float* agg  = h + (size_t)n * 128;     // n*128

    hipMemsetAsync(deg, 0, (size_t)n * sizeof(float), stream);
    hipMemsetAsync(agg, 0, (size_t)n * 128 * sizeof(float), stream);

    k_degree<<<1024, BLOCK, 0, stream>>>(dst, E, deg);
    k_dinv<<<(n + BLOCK - 1) / BLOCK, BLOCK, 0, stream>>>(deg, dinv, n);
    k_gemm_xw<<<(n + 63) / 64, BLOCK, 0, stream>>>(x, Wg, h, n);
    k_scatter<<<4096, BLOCK, 0, stream>>>(src, dst, E, dinv, h, agg);
    k_final<<<(n + 63) / 64, BLOCK, 0, stream>>>(agg, h, deg, bg, Wh, bh, Wl, bl, out, n);
}

// Round 2
// 589.586 us; speedup vs baseline: 2.0661x; 2.0661x over previous
//
#include <hip/hip_runtime.h>

// GCNConv(100k nodes, 1M edges, D=128) + two heads (128->64), fp32.
// R2: replace fp32 atomic scatter (820us, 1GB write-through) with CSR build +
// gather-side reduction (no float atomics).
//
// ws layout: deg_i[n] (int) | off[n+1] (int) | cursor[n] (int) | bsum[nb] (int)
//            | csr_src[E] (int) | dinv[n] | h[n*128] | hf[n*128]   (~108 MB)

#define BLOCK 256

__global__ __launch_bounds__(BLOCK) void k_count(const int* __restrict__ dst, int E,
                                                 int* __restrict__ deg_i) {
    int i = blockIdx.x * blockDim.x + threadIdx.x;
    int stride = gridDim.x * blockDim.x;
    for (int e = i; e < E; e += stride) atomicAdd(&deg_i[dst[e]], 1);
}

__global__ __launch_bounds__(BLOCK) void k_scan1(const int* __restrict__ deg_i,
                                                 int* __restrict__ off,
                                                 int* __restrict__ bsum, int n) {
    __shared__ int tmp[BLOCK];
    int gid = blockIdx.x * BLOCK + threadIdx.x;
    int v = (gid < n) ? deg_i[gid] : 0;
    tmp[threadIdx.x] = v;
    __syncthreads();
    for (int ofs = 1; ofs < BLOCK; ofs <<= 1) {
        int t = (threadIdx.x >= ofs) ? tmp[threadIdx.x - ofs] : 0;
        __syncthreads();
        tmp[threadIdx.x] += t;
        __syncthreads();
    }
    if (gid < n) off[gid] = tmp[threadIdx.x] - v;  // exclusive within block
    if (threadIdx.x == BLOCK - 1) bsum[blockIdx.x] = tmp[threadIdx.x];
}

__global__ void k_scan2(int* __restrict__ bsum, int nb, int* __restrict__ off,
                        int n, int E) {
    if (threadIdx.x == 0 && blockIdx.x == 0) {
        int acc = 0;
        for (int i = 0; i < nb; i++) { int t = bsum[i]; bsum[i] = acc; acc += t; }
        off[n] = E;
    }
}

__global__ __launch_bounds__(BLOCK) void k_scan3(int* __restrict__ off,
                                                 const int* __restrict__ bsum, int n) {
    int gid = blockIdx.x * BLOCK + threadIdx.x;
    if (gid < n) off[gid] += bsum[blockIdx.x];
}

__global__ __launch_bounds__(BLOCK) void k_fill(const int* __restrict__ src,
                                                const int* __restrict__ dst, int E,
                                                const int* __restrict__ off,
                                                int* __restrict__ cursor,
                                                int* __restrict__ csr_src) {
    int i = blockIdx.x * blockDim.x + threadIdx.x;
    int stride = gridDim.x * blockDim.x;
    for (int e = i; e < E; e += stride) {
        int d = dst[e];
        int pos = atomicAdd(&cursor[d], 1);
        csr_src[off[d] + pos] = src[e];
    }
}

__global__ __launch_bounds__(BLOCK) void k_dinv(const int* __restrict__ deg_i,
                                                float* __restrict__ dinv, int n) {
    int i = blockIdx.x * blockDim.x + threadIdx.x;
    if (i < n) dinv[i] = rsqrtf((float)(deg_i[i] + 1));  // +1 self-loop
}

// h = x @ W   (n x 128) * (128 x 128), W staged in LDS
__global__ __launch_bounds__(BLOCK) void k_gemm_xw(const float* __restrict__ x,
                                                   const float* __restrict__ W,
                                                   float* __restrict__ h, int n) {
    __shared__ float Ws[128 * 128];
    const float4* W4 = (const float4*)W;
    float4* Ws4 = (float4*)Ws;
    for (int i = threadIdx.x; i < 128 * 32; i += BLOCK) Ws4[i] = W4[i];
    __syncthreads();

    int row = blockIdx.x * 64 + (threadIdx.x >> 2);
    if (row >= n) return;
    int cg = threadIdx.x & 3;

    float acc[32];
#pragma unroll
    for (int j = 0; j < 32; j++) acc[j] = 0.f;

    const float4* xrow4 = (const float4*)(x + (size_t)row * 128);
    for (int k4 = 0; k4 < 32; k4++) {
        float4 xv = xrow4[k4];
#pragma unroll
        for (int kk = 0; kk < 4; kk++) {
            float xs = (&xv.x)[kk];
            int k = k4 * 4 + kk;
            const float4* wrow = (const float4*)(Ws + k * 128 + cg * 32);
#pragma unroll
            for (int j4 = 0; j4 < 8; j4++) {
                float4 wv = wrow[j4];
                acc[j4 * 4 + 0] += xs * wv.x;
                acc[j4 * 4 + 1] += xs * wv.y;
                acc[j4 * 4 + 2] += xs * wv.z;
                acc[j4 * 4 + 3] += xs * wv.w;
            }
        }
    }
    float4* hout = (float4*)(h + (size_t)row * 128 + cg * 32);
#pragma unroll
    for (int j4 = 0; j4 < 8; j4++)
        hout[j4] = make_float4(acc[j4 * 4 + 0], acc[j4 * 4 + 1],
                               acc[j4 * 4 + 2], acc[j4 * 4 + 3]);
}

// one wave per dst node: hf[d] = dinv[d]*sum(dinv[s]*h[s]) + dinv[d]^2*h[d] + b_gcn
__global__ __launch_bounds__(BLOCK) void k_gather(const int* __restrict__ off,
                                                  const int* __restrict__ csr_src,
                                                  const float* __restrict__ dinv,
                                                  const float* __restrict__ h,
                                                  const float* __restrict__ bg,
                                                  float* __restrict__ hf, int n) {
    int wave = (blockIdx.x * blockDim.x + threadIdx.x) >> 6;
    int lane = threadIdx.x & 63;
    if (wave >= n) return;
    int d = wave;
    int beg = off[d], end = off[d + 1];

    float2 acc = make_float2(0.f, 0.f);
    for (int i = beg; i < end; i++) {
        int s = csr_src[i];
        float w = dinv[s];
        float2 v = ((const float2*)(h + (size_t)s * 128))[lane];
        acc.x += w * v.x;
        acc.y += w * v.y;
    }
    float dv = dinv[d];
    float inv = dv * dv;
    float2 hv = ((const float2*)(h + (size_t)d * 128))[lane];
    float2 bv = ((const float2*)bg)[lane];
    float2 o;
    o.x = dv * acc.x + inv * hv.x + bv.x;
    o.y = dv * acc.y + inv * hv.y + bv.y;
    ((float2*)(hf + (size_t)d * 128))[lane] = o;
}

// out = hf @ [W_high | W_low] + [b_high | b_low]
__global__ __launch_bounds__(BLOCK) void k_final2(const float* __restrict__ hf,
                                                  const float* __restrict__ Wh,
                                                  const float* __restrict__ bh,
                                                  const float* __restrict__ Wl,
                                                  const float* __restrict__ bl,
                                                  float* __restrict__ out, int n) {
    __shared__ float Wc[128 * 128];  // [k][c]: c<64 -> W_high, c>=64 -> W_low
    for (int i = threadIdx.x; i < 128 * 64; i += BLOCK) {
        int k = i >> 6, c = i & 63;
        Wc[k * 128 + c] = Wh[k * 64 + c];
        Wc[k * 128 + 64 + c] = Wl[k * 64 + c];
    }
    __syncthreads();

    int row = blockIdx.x * 64 + (threadIdx.x >> 2);
    if (row >= n) return;
    int cg = threadIdx.x & 3;

    float acc[32];
#pragma unroll
    for (int j = 0; j < 32; j++) {
        int c = cg * 32 + j;
        acc[j] = (c < 64) ? bh[c] : bl[c - 64];
    }

    const float4* a4 = (const float4*)(hf + (size_t)row * 128);
    for (int k4 = 0; k4 < 32; k4++) {
        float4 av = a4[k4];
#pragma unroll
        for (int kk = 0; kk < 4; kk++) {
            float hs = (&av.x)[kk];
            int k = k4 * 4 + kk;
            const float4* wrow = (const float4*)(Wc + k * 128 + cg * 32);
#pragma unroll
            for (int j4 = 0; j4 < 8; j4++) {
                float4 wv = wrow[j4];
                acc[j4 * 4 + 0] += hs * wv.x;
                acc[j4 * 4 + 1] += hs * wv.y;
                acc[j4 * 4 + 2] += hs * wv.z;
                acc[j4 * 4 + 3] += hs * wv.w;
            }
        }
    }

    float* high = out;
    float* low = out + (size_t)n * 64;
#pragma unroll
    for (int j4 = 0; j4 < 8; j4++) {
        int c = cg * 32 + j4 * 4;
        float4 v = make_float4(acc[j4 * 4 + 0], acc[j4 * 4 + 1],
                               acc[j4 * 4 + 2], acc[j4 * 4 + 3]);
        if (c < 64)
            ((float4*)(high + (size_t)row * 64))[c >> 2] = v;
        else
            ((float4*)(low + (size_t)row * 64))[(c - 64) >> 2] = v;
    }
}

extern "C" void kernel_launch(void* const* d_in, const int* in_sizes, int n_in,
                              void* d_out, int out_size, void* d_ws, size_t ws_size,
                              hipStream_t stream) {
    const float* x  = (const float*)d_in[0];
    const int*   ei = (const int*)d_in[1];
    const float* Wg = (const float*)d_in[2];
    const float* bg = (const float*)d_in[3];
    const float* Wh = (const float*)d_in[4];
    const float* bh = (const float*)d_in[5];
    const float* Wl = (const float*)d_in[6];
    const float* bl = (const float*)d_in[7];
    float* out = (float*)d_out;

    int n = in_sizes[0] / 128;  // 100000
    int E = in_sizes[1] / 2;    // 1000000
    const int* src = ei;
    const int* dst = ei + E;
    int nb = (n + BLOCK - 1) / BLOCK;  // scan blocks

    char* ws = (char*)d_ws;
    int*   deg_i  = (int*)ws;                     ws += (size_t)n * 4;
    int*   off    = (int*)ws;                     ws += (size_t)(n + 1) * 4;
    int*   cursor = (int*)ws;                     ws += (size_t)n * 4;
    int*   bsum   = (int*)ws;                     ws += (size_t)nb * 4;
    int*   csr    = (int*)ws;                     ws += (size_t)E * 4;
    float* dinv   = (float*)ws;                   ws += (size_t)n * 4;
    float* h      = (float*)ws;                   ws += (size_t)n * 128 * 4;
    float* hf     = (float*)ws;

    hipMemsetAsync(deg_i, 0, (size_t)n * sizeof(int), stream);
    hipMemsetAsync(cursor, 0, (size_t)n * sizeof(int), stream);

    k_count<<<1024, BLOCK, 0, stream>>>(dst, E, deg_i);
    k_scan1<<<nb, BLOCK, 0, stream>>>(deg_i, off, bsum, n);
    k_scan2<<<1, 64, 0, stream>>>(bsum, nb, off, n, E);
    k_scan3<<<nb, BLOCK, 0, stream>>>(off, bsum, n);
    k_fill<<<1024, BLOCK, 0, stream>>>(src, dst, E, off, cursor, csr);
    k_dinv<<<(n + BLOCK - 1) / BLOCK, BLOCK, 0, stream>>>(deg_i, dinv, n);
    k_gemm_xw<<<(n + 63) / 64, BLOCK, 0, stream>>>(x, Wg, h, n);
    k_gather<<<((size_t)n * 64 + BLOCK - 1) / BLOCK, BLOCK, 0, stream>>>(off, csr, dinv, h, bg, hf, n);
    k_final2<<<(n + 63) / 64, BLOCK, 0, stream>>>(hf, Wh, bh, Wl, bl, out, n);
}

// Round 4
// 488.994 us; speedup vs baseline: 2.4911x; 1.2057x over previous
//
#include <hip/hip_runtime.h>

// GCNConv(100k nodes, 1M edges, D=128) + two heads (128->64), fp32.
// R4: fix R3's UB (indexing 16 floats through &w0.x across 4 separate float4
// locals -> garbage). Use proper local arrays; structure otherwise identical.
//
// ws: deg_i[n] | off[n+1] | cursor[n] | bsum[nb] | csr_src[E] | dinv[n]
//     | h[n*128] | hf[n*128]

#define BLOCK 256
#define BM 128
#define BK 32

// ---------------- CSR build ----------------

__global__ __launch_bounds__(BLOCK) void k_count(const int* __restrict__ dst, int E,
                                                 int* __restrict__ deg_i) {
    int i = blockIdx.x * blockDim.x + threadIdx.x;
    int stride = gridDim.x * blockDim.x;
    for (int e = i; e < E; e += stride) atomicAdd(&deg_i[dst[e]], 1);
}

__global__ __launch_bounds__(BLOCK) void k_scan1(const int* __restrict__ deg_i,
                                                 int* __restrict__ off,
                                                 int* __restrict__ bsum, int n) {
    __shared__ int tmp[BLOCK];
    int gid = blockIdx.x * BLOCK + threadIdx.x;
    int v = (gid < n) ? deg_i[gid] : 0;
    tmp[threadIdx.x] = v;
    __syncthreads();
    for (int ofs = 1; ofs < BLOCK; ofs <<= 1) {
        int t = (threadIdx.x >= ofs) ? tmp[threadIdx.x - ofs] : 0;
        __syncthreads();
        tmp[threadIdx.x] += t;
        __syncthreads();
    }
    if (gid < n) off[gid] = tmp[threadIdx.x] - v;
    if (threadIdx.x == BLOCK - 1) bsum[blockIdx.x] = tmp[threadIdx.x];
}

__global__ void k_scan2(int* __restrict__ bsum, int nb, int* __restrict__ off,
                        int n, int E) {
    if (threadIdx.x == 0 && blockIdx.x == 0) {
        int acc = 0;
        for (int i = 0; i < nb; i++) { int t = bsum[i]; bsum[i] = acc; acc += t; }
        off[n] = E;
    }
}

__global__ __launch_bounds__(BLOCK) void k_scan3(int* __restrict__ off,
                                                 const int* __restrict__ bsum, int n) {
    int gid = blockIdx.x * BLOCK + threadIdx.x;
    if (gid < n) off[gid] += bsum[blockIdx.x];
}

__global__ __launch_bounds__(BLOCK) void k_fill(const int* __restrict__ src,
                                                const int* __restrict__ dst, int E,
                                                const int* __restrict__ off,
                                                int* __restrict__ cursor,
                                                int* __restrict__ csr_src) {
    int i = blockIdx.x * blockDim.x + threadIdx.x;
    int stride = gridDim.x * blockDim.x;
    for (int e = i; e < E; e += stride) {
        int d = dst[e];
        int pos = atomicAdd(&cursor[d], 1);
        csr_src[off[d] + pos] = src[e];
    }
}

__global__ __launch_bounds__(BLOCK) void k_dinv(const int* __restrict__ deg_i,
                                                float* __restrict__ dinv, int n) {
    int i = blockIdx.x * blockDim.x + threadIdx.x;
    if (i < n) dinv[i] = rsqrtf((float)(deg_i[i] + 1));
}

// ---------------- tiled GEMM: h = x @ W ----------------
// block tile 128 rows x 128 cols, BK=32; thread tile 4 rows x 16 cols.

__global__ __launch_bounds__(BLOCK) void k_gemm_xw(const float* __restrict__ x,
                                                   const float* __restrict__ W,
                                                   float* __restrict__ h, int n) {
    __shared__ float Xs[BK][BM];  // [k][row]
    __shared__ float Ws[BK][BM];  // [k][col]
    int rg = threadIdx.x >> 3;
    int cg = threadIdx.x & 7;
    int row0 = blockIdx.x * BM;

    float acc[4][16];
#pragma unroll
    for (int r = 0; r < 4; r++)
#pragma unroll
        for (int j = 0; j < 16; j++) acc[r][j] = 0.f;

    for (int kt = 0; kt < 128; kt += BK) {
        int kt4 = kt >> 2;
#pragma unroll
        for (int i = 0; i < 4; i++) {
            int s = threadIdx.x + i * 256;
            int r = s >> 3;
            int c4 = s & 7;
            int gr = row0 + r;
            if (gr >= n) gr = n - 1;
            float4 v = ((const float4*)(x + (size_t)gr * 128))[kt4 + c4];
            Xs[c4 * 4 + 0][r] = v.x;
            Xs[c4 * 4 + 1][r] = v.y;
            Xs[c4 * 4 + 2][r] = v.z;
            Xs[c4 * 4 + 3][r] = v.w;
        }
#pragma unroll
        for (int i = 0; i < 4; i++) {
            int s = threadIdx.x + i * 256;
            int k = s >> 5;
            int c4 = s & 31;
            float4 v = ((const float4*)(W + (size_t)(kt + k) * 128))[c4];
            *(float4*)&Ws[k][c4 * 4] = v;
        }
        __syncthreads();

#pragma unroll 4
        for (int k = 0; k < BK; k++) {
            float xf[4];
            *(float4*)xf = *(const float4*)&Xs[k][rg * 4];
            float wf[16];
            const float4* wrow = (const float4*)&Ws[k][cg * 16];
            ((float4*)wf)[0] = wrow[0];
            ((float4*)wf)[1] = wrow[1];
            ((float4*)wf)[2] = wrow[2];
            ((float4*)wf)[3] = wrow[3];
#pragma unroll
            for (int r = 0; r < 4; r++)
#pragma unroll
                for (int j = 0; j < 16; j++) acc[r][j] += xf[r] * wf[j];
        }
        __syncthreads();
    }

#pragma unroll
    for (int r = 0; r < 4; r++) {
        int row = row0 + rg * 4 + r;
        if (row >= n) break;
        float4* hout = (float4*)(h + (size_t)row * 128 + cg * 16);
#pragma unroll
        for (int j4 = 0; j4 < 4; j4++)
            hout[j4] = make_float4(acc[r][j4 * 4 + 0], acc[r][j4 * 4 + 1],
                                   acc[r][j4 * 4 + 2], acc[r][j4 * 4 + 3]);
    }
}

// ---------------- gather ----------------

__global__ __launch_bounds__(BLOCK) void k_gather(const int* __restrict__ off,
                                                  const int* __restrict__ csr_src,
                                                  const float* __restrict__ dinv,
                                                  const float* __restrict__ h,
                                                  const float* __restrict__ bg,
                                                  float* __restrict__ hf, int n) {
    int wave = (blockIdx.x * blockDim.x + threadIdx.x) >> 6;
    int lane = threadIdx.x & 63;
    if (wave >= n) return;
    int d = wave;
    int beg = off[d], end = off[d + 1];

    float2 acc = make_float2(0.f, 0.f);
    for (int i = beg; i < end; i++) {
        int s = csr_src[i];
        float w = dinv[s];
        float2 v = ((const float2*)(h + (size_t)s * 128))[lane];
        acc.x += w * v.x;
        acc.y += w * v.y;
    }
    float dv = dinv[d];
    float inv = dv * dv;
    float2 hv = ((const float2*)(h + (size_t)d * 128))[lane];
    float2 bv = ((const float2*)bg)[lane];
    float2 o;
    o.x = dv * acc.x + inv * hv.x + bv.x;
    o.y = dv * acc.y + inv * hv.y + bv.y;
    ((float2*)(hf + (size_t)d * 128))[lane] = o;
}

// ---------------- tiled GEMM: out = hf @ [Wh|Wl] + [bh|bl] ----------------

__global__ __launch_bounds__(BLOCK) void k_final2(const float* __restrict__ hf,
                                                  const float* __restrict__ Wh,
                                                  const float* __restrict__ bh,
                                                  const float* __restrict__ Wl,
                                                  const float* __restrict__ bl,
                                                  float* __restrict__ out, int n) {
    __shared__ float Xs[BK][BM];
    __shared__ float Ws[BK][BM];  // cols 0..63 = Wh, 64..127 = Wl
    int rg = threadIdx.x >> 3;
    int cg = threadIdx.x & 7;
    int row0 = blockIdx.x * BM;

    float acc[4][16];
#pragma unroll
    for (int r = 0; r < 4; r++)
#pragma unroll
        for (int j = 0; j < 16; j++) acc[r][j] = 0.f;

    for (int kt = 0; kt < 128; kt += BK) {
        int kt4 = kt >> 2;
#pragma unroll
        for (int i = 0; i < 4; i++) {
            int s = threadIdx.x + i * 256;
            int r = s >> 3;
            int c4 = s & 7;
            int gr = row0 + r;
            if (gr >= n) gr = n - 1;
            float4 v = ((const float4*)(hf + (size_t)gr * 128))[kt4 + c4];
            Xs[c4 * 4 + 0][r] = v.x;
            Xs[c4 * 4 + 1][r] = v.y;
            Xs[c4 * 4 + 2][r] = v.z;
            Xs[c4 * 4 + 3][r] = v.w;
        }
#pragma unroll
        for (int i = 0; i < 4; i++) {
            int s = threadIdx.x + i * 256;
            int k = s >> 5;
            int c4 = s & 31;
            int c = c4 * 4;
            float4 v;
            if (c < 64)
                v = ((const float4*)(Wh + (size_t)(kt + k) * 64))[c4];
            else
                v = ((const float4*)(Wl + (size_t)(kt + k) * 64))[c4 - 16];
            *(float4*)&Ws[k][c] = v;
        }
        __syncthreads();

#pragma unroll 4
        for (int k = 0; k < BK; k++) {
            float xf[4];
            *(float4*)xf = *(const float4*)&Xs[k][rg * 4];
            float wf[16];
            const float4* wrow = (const float4*)&Ws[k][cg * 16];
            ((float4*)wf)[0] = wrow[0];
            ((float4*)wf)[1] = wrow[1];
            ((float4*)wf)[2] = wrow[2];
            ((float4*)wf)[3] = wrow[3];
#pragma unroll
            for (int r = 0; r < 4; r++)
#pragma unroll
                for (int j = 0; j < 16; j++) acc[r][j] += xf[r] * wf[j];
        }
        __syncthreads();
    }

    // bias + split store: cg<4 -> high cols cg*16.., cg>=4 -> low cols (cg-4)*16..
    const float* bias = (cg < 4) ? (bh + cg * 16) : (bl + (cg - 4) * 16);
    float bvf[16];
#pragma unroll
    for (int j4 = 0; j4 < 4; j4++) ((float4*)bvf)[j4] = ((const float4*)bias)[j4];

#pragma unroll
    for (int r = 0; r < 4; r++) {
        int row = row0 + rg * 4 + r;
        if (row >= n) break;
        float* base = (cg < 4) ? (out + (size_t)row * 64 + cg * 16)
                               : (out + (size_t)n * 64 + (size_t)row * 64 + (cg - 4) * 16);
#pragma unroll
        for (int j4 = 0; j4 < 4; j4++) {
            float4 v = make_float4(acc[r][j4 * 4 + 0] + bvf[j4 * 4 + 0],
                                   acc[r][j4 * 4 + 1] + bvf[j4 * 4 + 1],
                                   acc[r][j4 * 4 + 2] + bvf[j4 * 4 + 2],
                                   acc[r][j4 * 4 + 3] + bvf[j4 * 4 + 3]);
            ((float4*)base)[j4] = v;
        }
    }
}

extern "C" void kernel_launch(void* const* d_in, const int* in_sizes, int n_in,
                              void* d_out, int out_size, void* d_ws, size_t ws_size,
                              hipStream_t stream) {
    const float* x  = (const float*)d_in[0];
    const int*   ei = (const int*)d_in[1];
    const float* Wg = (const float*)d_in[2];
    const float* bg = (const float*)d_in[3];
    const float* Wh = (const float*)d_in[4];
    const float* bh = (const float*)d_in[5];
    const float* Wl = (const float*)d_in[6];
    const float* bl = (const float*)d_in[7];
    float* out = (float*)d_out;

    int n = in_sizes[0] / 128;
    int E = in_sizes[1] / 2;
    const int* src = ei;
    const int* dst = ei + E;
    int nb = (n + BLOCK - 1) / BLOCK;

    char* ws = (char*)d_ws;
    int*   deg_i  = (int*)ws;                     ws += (size_t)n * 4;
    int*   off    = (int*)ws;                     ws += (size_t)(n + 1) * 4;
    int*   cursor = (int*)ws;                     ws += (size_t)n * 4;
    int*   bsum   = (int*)ws;                     ws += (size_t)nb * 4;
    int*   csr    = (int*)ws;                     ws += (size_t)E * 4;
    float* dinv   = (float*)ws;                   ws += (size_t)n * 4;
    float* h      = (float*)ws;                   ws += (size_t)n * 128 * 4;
    float* hf     = (float*)ws;

    hipMemsetAsync(deg_i, 0, (size_t)n * sizeof(int), stream);
    hipMemsetAsync(cursor, 0, (size_t)n * sizeof(int), stream);

    k_count<<<1024, BLOCK, 0, stream>>>(dst, E, deg_i);
    k_scan1<<<nb, BLOCK, 0, stream>>>(deg_i, off, bsum, n);
    k_scan2<<<1, 64, 0, stream>>>(bsum, nb, off, n, E);
    k_scan3<<<nb, BLOCK, 0, stream>>>(off, bsum, n);
    k_fill<<<1024, BLOCK, 0, stream>>>(src, dst, E, off, cursor, csr);
    k_dinv<<<(n + BLOCK - 1) / BLOCK, BLOCK, 0, stream>>>(deg_i, dinv, n);
    k_gemm_xw<<<(n + BM - 1) / BM, BLOCK, 0, stream>>>(x, Wg, h, n);
    k_gather<<<((size_t)n * 64 + BLOCK - 1) / BLOCK, BLOCK, 0, stream>>>(off, csr, dinv, h, bg, hf, n);
    k_final2<<<(n + BM - 1) / BM, BLOCK, 0, stream>>>(hf, Wh, bh, Wl, bl, out, n);
}

// Round 5
// 421.427 us; speedup vs baseline: 2.8905x; 1.1603x over previous
//
#include <hip/hip_runtime.h>

// GCNConv(100k nodes, 1M edges, D=128) + two heads (128->64), fp32.
// R5: (1) fold the whole linear chain into ONE GEMM via Wf = Wg@[Wh|Wl],
//     bf = bg@[Wh|Wl] + [bh|bl]; gather runs over x directly.
//     (2) gather rewritten with index-prefetch + shfl broadcast + 4x unrolled
//     independent row loads (breaks the serial load->load dependence).
//
// ws: deg_i[n] | off[n+1] | cursor[n] | bsum[nb] | csr_src[E] | dinv[n]
//     | aggx[n*128] | Wf[128*128] | bf[128]

#define BLOCK 256
#define BM 128
#define BK 32

// ---------------- CSR build ----------------

__global__ __launch_bounds__(BLOCK) void k_count(const int* __restrict__ dst, int E,
                                                 int* __restrict__ deg_i) {
    int i = blockIdx.x * blockDim.x + threadIdx.x;
    int stride = gridDim.x * blockDim.x;
    for (int e = i; e < E; e += stride) atomicAdd(&deg_i[dst[e]], 1);
}

__global__ __launch_bounds__(BLOCK) void k_scan1(const int* __restrict__ deg_i,
                                                 int* __restrict__ off,
                                                 int* __restrict__ bsum, int n) {
    __shared__ int tmp[BLOCK];
    int gid = blockIdx.x * BLOCK + threadIdx.x;
    int v = (gid < n) ? deg_i[gid] : 0;
    tmp[threadIdx.x] = v;
    __syncthreads();
    for (int ofs = 1; ofs < BLOCK; ofs <<= 1) {
        int t = (threadIdx.x >= ofs) ? tmp[threadIdx.x - ofs] : 0;
        __syncthreads();
        tmp[threadIdx.x] += t;
        __syncthreads();
    }
    if (gid < n) off[gid] = tmp[threadIdx.x] - v;
    if (threadIdx.x == BLOCK - 1) bsum[blockIdx.x] = tmp[threadIdx.x];
}

__global__ void k_scan2(int* __restrict__ bsum, int nb, int* __restrict__ off,
                        int n, int E) {
    if (threadIdx.x == 0 && blockIdx.x == 0) {
        int acc = 0;
        for (int i = 0; i < nb; i++) { int t = bsum[i]; bsum[i] = acc; acc += t; }
        off[n] = E;
    }
}

__global__ __launch_bounds__(BLOCK) void k_scan3(int* __restrict__ off,
                                                 const int* __restrict__ bsum, int n) {
    int gid = blockIdx.x * BLOCK + threadIdx.x;
    if (gid < n) off[gid] += bsum[blockIdx.x];
}

__global__ __launch_bounds__(BLOCK) void k_fill(const int* __restrict__ src,
                                                const int* __restrict__ dst, int E,
                                                const int* __restrict__ off,
                                                int* __restrict__ cursor,
                                                int* __restrict__ csr_src) {
    int i = blockIdx.x * blockDim.x + threadIdx.x;
    int stride = gridDim.x * blockDim.x;
    for (int e = i; e < E; e += stride) {
        int d = dst[e];
        int pos = atomicAdd(&cursor[d], 1);
        csr_src[off[d] + pos] = src[e];
    }
}

__global__ __launch_bounds__(BLOCK) void k_dinv(const int* __restrict__ deg_i,
                                                float* __restrict__ dinv, int n) {
    int i = blockIdx.x * blockDim.x + threadIdx.x;
    if (i < n) dinv[i] = rsqrtf((float)(deg_i[i] + 1));
}

// ---------------- weight fusion: Wf = Wg @ [Wh|Wl], bf = bg @ [Wh|Wl] + [bh|bl] ----------------
// blocks 0..15: 8 rows of Wf each (thread = 1 row x 4 cols); block 16: bf.

__global__ __launch_bounds__(BLOCK) void k_fuse(const float* __restrict__ Wg,
                                                const float* __restrict__ Wh,
                                                const float* __restrict__ Wl,
                                                const float* __restrict__ bg,
                                                const float* __restrict__ bh,
                                                const float* __restrict__ bl,
                                                float* __restrict__ Wf,
                                                float* __restrict__ bf) {
    if (blockIdx.x == 16) {
        int c = threadIdx.x;
        if (c < 128) {
            float acc = (c < 64) ? bh[c] : bl[c - 64];
            for (int j = 0; j < 128; j++) {
                float wc = (c < 64) ? Wh[j * 64 + c] : Wl[j * 64 + (c - 64)];
                acc += bg[j] * wc;
            }
            bf[c] = acc;
        }
        return;
    }
    int r = blockIdx.x * 8 + (threadIdx.x >> 5);
    int c0 = (threadIdx.x & 31) * 4;
    float a0 = 0.f, a1 = 0.f, a2 = 0.f, a3 = 0.f;
    for (int j = 0; j < 128; j++) {
        float wg = Wg[r * 128 + j];
        float4 wc;
        if (c0 < 64) wc = *(const float4*)(Wh + j * 64 + c0);
        else         wc = *(const float4*)(Wl + j * 64 + (c0 - 64));
        a0 += wg * wc.x; a1 += wg * wc.y; a2 += wg * wc.z; a3 += wg * wc.w;
    }
    *(float4*)(Wf + r * 128 + c0) = make_float4(a0, a1, a2, a3);
}

// ---------------- gather over x: aggx[d] = dinv[d]*sum(dinv[s]*x[s]) + dinv[d]^2*x[d] ----------------
// one wave per dst node; indices prefetched per 64-chunk, shfl-broadcast,
// 4x-unrolled independent row loads for MLP.

__global__ __launch_bounds__(BLOCK) void k_gather(const int* __restrict__ off,
                                                  const int* __restrict__ csr_src,
                                                  const float* __restrict__ dinv,
                                                  const float* __restrict__ x,
                                                  float* __restrict__ aggx, int n) {
    int wave = (blockIdx.x * blockDim.x + threadIdx.x) >> 6;
    int lane = threadIdx.x & 63;
    if (wave >= n) return;
    int d = wave;
    int beg = off[d], end = off[d + 1];

    float accx = 0.f, accy = 0.f;
    for (int base = beg; base < end; base += 64) {
        int cnt = min(64, end - base);
        int s = 0; float w = 0.f;
        if (lane < cnt) { s = csr_src[base + lane]; w = dinv[s]; }
        int j = 0;
        for (; j + 4 <= cnt; j += 4) {
            int s0 = __shfl(s, j);
            int s1 = __shfl(s, j + 1);
            int s2 = __shfl(s, j + 2);
            int s3 = __shfl(s, j + 3);
            float w0 = __shfl(w, j);
            float w1 = __shfl(w, j + 1);
            float w2 = __shfl(w, j + 2);
            float w3 = __shfl(w, j + 3);
            float2 v0 = ((const float2*)(x + (size_t)s0 * 128))[lane];
            float2 v1 = ((const float2*)(x + (size_t)s1 * 128))[lane];
            float2 v2 = ((const float2*)(x + (size_t)s2 * 128))[lane];
            float2 v3 = ((const float2*)(x + (size_t)s3 * 128))[lane];
            accx += w0 * v0.x + w1 * v1.x + w2 * v2.x + w3 * v3.x;
            accy += w0 * v0.y + w1 * v1.y + w2 * v2.y + w3 * v3.y;
        }
        for (; j < cnt; j++) {
            int sj = __shfl(s, j);
            float wj = __shfl(w, j);
            float2 v = ((const float2*)(x + (size_t)sj * 128))[lane];
            accx += wj * v.x;
            accy += wj * v.y;
        }
    }
    float dv = dinv[d];
    float2 xv = ((const float2*)(x + (size_t)d * 128))[lane];
    float2 o;
    o.x = dv * accx + dv * dv * xv.x;
    o.y = dv * accy + dv * dv * xv.y;
    ((float2*)(aggx + (size_t)d * 128))[lane] = o;
}

// ---------------- tiled GEMM: out = aggx @ Wf + bf (split high/low store) ----------------

__global__ __launch_bounds__(BLOCK) void k_final(const float* __restrict__ aggx,
                                                 const float* __restrict__ Wf,
                                                 const float* __restrict__ bf,
                                                 float* __restrict__ out, int n) {
    __shared__ float Xs[BK][BM];  // [k][row]
    __shared__ float Ws[BK][BM];  // [k][col] fused cols
    int rg = threadIdx.x >> 3;
    int cg = threadIdx.x & 7;
    int row0 = blockIdx.x * BM;

    float acc[4][16];
#pragma unroll
    for (int r = 0; r < 4; r++)
#pragma unroll
        for (int j = 0; j < 16; j++) acc[r][j] = 0.f;

    for (int kt = 0; kt < 128; kt += BK) {
        int kt4 = kt >> 2;
#pragma unroll
        for (int i = 0; i < 4; i++) {
            int s = threadIdx.x + i * 256;
            int r = s >> 3;
            int c4 = s & 7;
            int gr = row0 + r;
            if (gr >= n) gr = n - 1;
            float4 v = ((const float4*)(aggx + (size_t)gr * 128))[kt4 + c4];
            Xs[c4 * 4 + 0][r] = v.x;
            Xs[c4 * 4 + 1][r] = v.y;
            Xs[c4 * 4 + 2][r] = v.z;
            Xs[c4 * 4 + 3][r] = v.w;
        }
#pragma unroll
        for (int i = 0; i < 4; i++) {
            int s = threadIdx.x + i * 256;
            int k = s >> 5;
            int c4 = s & 31;
            float4 v = ((const float4*)(Wf + (size_t)(kt + k) * 128))[c4];
            *(float4*)&Ws[k][c4 * 4] = v;
        }
        __syncthreads();

#pragma unroll 4
        for (int k = 0; k < BK; k++) {
            float xf[4];
            *(float4*)xf = *(const float4*)&Xs[k][rg * 4];
            float wf[16];
            const float4* wrow = (const float4*)&Ws[k][cg * 16];
            ((float4*)wf)[0] = wrow[0];
            ((float4*)wf)[1] = wrow[1];
            ((float4*)wf)[2] = wrow[2];
            ((float4*)wf)[3] = wrow[3];
#pragma unroll
            for (int r = 0; r < 4; r++)
#pragma unroll
                for (int j = 0; j < 16; j++) acc[r][j] += xf[r] * wf[j];
        }
        __syncthreads();
    }

    float bvf[16];
#pragma unroll
    for (int j4 = 0; j4 < 4; j4++)
        ((float4*)bvf)[j4] = ((const float4*)(bf + cg * 16))[j4];

#pragma unroll
    for (int r = 0; r < 4; r++) {
        int row = row0 + rg * 4 + r;
        if (row >= n) break;
        float* base = (cg < 4) ? (out + (size_t)row * 64 + cg * 16)
                               : (out + (size_t)n * 64 + (size_t)row * 64 + (cg - 4) * 16);
#pragma unroll
        for (int j4 = 0; j4 < 4; j4++) {
            float4 v = make_float4(acc[r][j4 * 4 + 0] + bvf[j4 * 4 + 0],
                                   acc[r][j4 * 4 + 1] + bvf[j4 * 4 + 1],
                                   acc[r][j4 * 4 + 2] + bvf[j4 * 4 + 2],
                                   acc[r][j4 * 4 + 3] + bvf[j4 * 4 + 3]);
            ((float4*)base)[j4] = v;
        }
    }
}

extern "C" void kernel_launch(void* const* d_in, const int* in_sizes, int n_in,
                              void* d_out, int out_size, void* d_ws, size_t ws_size,
                              hipStream_t stream) {
    const float* x  = (const float*)d_in[0];
    const int*   ei = (const int*)d_in[1];
    const float* Wg = (const float*)d_in[2];
    const float* bg = (const float*)d_in[3];
    const float* Wh = (const float*)d_in[4];
    const float* bh = (const float*)d_in[5];
    const float* Wl = (const float*)d_in[6];
    const float* bl = (const float*)d_in[7];
    float* out = (float*)d_out;

    int n = in_sizes[0] / 128;
    int E = in_sizes[1] / 2;
    const int* src = ei;
    const int* dst = ei + E;
    int nb = (n + BLOCK - 1) / BLOCK;

    char* ws = (char*)d_ws;
    int*   deg_i  = (int*)ws;                     ws += (size_t)n * 4;
    int*   off    = (int*)ws;                     ws += (size_t)(n + 1) * 4;
    int*   cursor = (int*)ws;                     ws += (size_t)n * 4;
    int*   bsum   = (int*)ws;                     ws += (size_t)nb * 4;
    int*   csr    = (int*)ws;                     ws += (size_t)E * 4;
    float* dinv   = (float*)ws;                   ws += (size_t)n * 4;
    float* aggx   = (float*)ws;                   ws += (size_t)n * 128 * 4;
    float* Wf     = (float*)ws;                   ws += (size_t)128 * 128 * 4;
    float* bf     = (float*)ws;

    hipMemsetAsync(deg_i, 0, (size_t)n * sizeof(int), stream);
    hipMemsetAsync(cursor, 0, (size_t)n * sizeof(int), stream);

    k_fuse<<<17, BLOCK, 0, stream>>>(Wg, Wh, Wl, bg, bh, bl, Wf, bf);
    k_count<<<1024, BLOCK, 0, stream>>>(dst, E, deg_i);
    k_scan1<<<nb, BLOCK, 0, stream>>>(deg_i, off, bsum, n);
    k_scan2<<<1, 64, 0, stream>>>(bsum, nb, off, n, E);
    k_scan3<<<nb, BLOCK, 0, stream>>>(off, bsum, n);
    k_fill<<<1024, BLOCK, 0, stream>>>(src, dst, E, off, cursor, csr);
    k_dinv<<<(n + BLOCK - 1) / BLOCK, BLOCK, 0, stream>>>(deg_i, dinv, n);
    k_gather<<<((size_t)n * 64 + BLOCK - 1) / BLOCK, BLOCK, 0, stream>>>(off, csr, dinv, x, aggx, n);
    k_final<<<(n + BM - 1) / BM, BLOCK, 0, stream>>>(aggx, Wf, bf, out, n);
}

// Round 6
// 350.260 us; speedup vs baseline: 3.4778x; 1.2032x over previous
//
#include <hip/hip_runtime.h>

// GCNConv(100k nodes, 1M edges, D=128) + two heads (128->64), fp32.
// R6: (1) gather payload in bf16 (x converted once) -> halves gather traffic;
//     (2) launch fusion: fuse+count+convert in one kernel; scan2+scan3+dinv+
//     cursor-zero in one kernel (parallel bsum prefix). 7 GPU ops vs 11.
//
// ws: deg_i[n] | off[n+1] | cursor[n] | bsum[nb] | csr[E] | dinv[n]
//     | aggx[n*128] f32 | Wf[128*128] | bf[128] | xh[n*128] bf16

#define BLOCK 256
#define BM 128
#define BK 32
#define CONV_BLOCKS 4096

__device__ inline unsigned short f2bf(float f) {
    unsigned u = __float_as_uint(f);
    unsigned r = (u + 0x7FFF + ((u >> 16) & 1)) >> 16;  // RNE
    return (unsigned short)r;
}
__device__ inline float bf2f(unsigned short u) {
    return __uint_as_float(((unsigned)u) << 16);
}

// ---------------- mega-prep: fuse weights | degree count | x -> bf16 ----------------
// blocks 0..15: Wf rows; 16: bf; 17..1040: count; 1041..: convert.

__global__ __launch_bounds__(BLOCK) void k_prep(const float* __restrict__ x,
                                                const int* __restrict__ dst, int E,
                                                const float* __restrict__ Wg,
                                                const float* __restrict__ Wh,
                                                const float* __restrict__ Wl,
                                                const float* __restrict__ bg,
                                                const float* __restrict__ bh,
                                                const float* __restrict__ bl,
                                                float* __restrict__ Wf,
                                                float* __restrict__ bf,
                                                int* __restrict__ deg_i,
                                                unsigned short* __restrict__ xh,
                                                int n) {
    int b = blockIdx.x;
    if (b < 16) {  // Wf = Wg @ [Wh|Wl]
        int r = b * 8 + (threadIdx.x >> 5);
        int c0 = (threadIdx.x & 31) * 4;
        float a0 = 0.f, a1 = 0.f, a2 = 0.f, a3 = 0.f;
        for (int j = 0; j < 128; j++) {
            float wg = Wg[r * 128 + j];
            float4 wc;
            if (c0 < 64) wc = *(const float4*)(Wh + j * 64 + c0);
            else         wc = *(const float4*)(Wl + j * 64 + (c0 - 64));
            a0 += wg * wc.x; a1 += wg * wc.y; a2 += wg * wc.z; a3 += wg * wc.w;
        }
        *(float4*)(Wf + r * 128 + c0) = make_float4(a0, a1, a2, a3);
    } else if (b == 16) {  // bf = bg @ [Wh|Wl] + [bh|bl]
        int c = threadIdx.x;
        if (c < 128) {
            float acc = (c < 64) ? bh[c] : bl[c - 64];
            for (int j = 0; j < 128; j++) {
                float wc = (c < 64) ? Wh[j * 64 + c] : Wl[j * 64 + (c - 64)];
                acc += bg[j] * wc;
            }
            bf[c] = acc;
        }
    } else if (b < 17 + 1024) {  // degree count
        int i = (b - 17) * BLOCK + threadIdx.x;
        int stride = 1024 * BLOCK;
        for (int e = i; e < E; e += stride) atomicAdd(&deg_i[dst[e]], 1);
    } else {  // x -> bf16, over n*32 float4s
        const float4* x4 = (const float4*)x;
        ushort4* o4 = (ushort4*)xh;
        int total = n * 32;
        int i = (b - 17 - 1024) * BLOCK + threadIdx.x;
        int stride = CONV_BLOCKS * BLOCK;
        for (; i < total; i += stride) {
            float4 v = x4[i];
            ushort4 o;
            o.x = f2bf(v.x); o.y = f2bf(v.y); o.z = f2bf(v.z); o.w = f2bf(v.w);
            o4[i] = o;
        }
    }
}

// ---------------- scan phase 1: per-block exclusive scan of deg ----------------

__global__ __launch_bounds__(BLOCK) void k_scan1(const int* __restrict__ deg_i,
                                                 int* __restrict__ off,
                                                 int* __restrict__ bsum, int n) {
    __shared__ int tmp[BLOCK];
    int gid = blockIdx.x * BLOCK + threadIdx.x;
    int v = (gid < n) ? deg_i[gid] : 0;
    tmp[threadIdx.x] = v;
    __syncthreads();
    for (int ofs = 1; ofs < BLOCK; ofs <<= 1) {
        int t = (threadIdx.x >= ofs) ? tmp[threadIdx.x - ofs] : 0;
        __syncthreads();
        tmp[threadIdx.x] += t;
        __syncthreads();
    }
    if (gid < n) off[gid] = tmp[threadIdx.x] - v;
    if (threadIdx.x == BLOCK - 1) bsum[blockIdx.x] = tmp[threadIdx.x];
}

// ---------------- scan phase 2: block prefix + dinv + cursor zero ----------------

__global__ __launch_bounds__(BLOCK) void k_scan3x(int* __restrict__ off,
                                                  const int* __restrict__ bsum,
                                                  const int* __restrict__ deg_i,
                                                  float* __restrict__ dinv,
                                                  int* __restrict__ cursor,
                                                  int n, int E) {
    __shared__ int tmp[BLOCK];
    int b = blockIdx.x;
    int partial = 0;
    for (int i = threadIdx.x; i < b; i += BLOCK) partial += bsum[i];
    tmp[threadIdx.x] = partial;
    __syncthreads();
    for (int s = BLOCK / 2; s > 0; s >>= 1) {
        if (threadIdx.x < s) tmp[threadIdx.x] += tmp[threadIdx.x + s];
        __syncthreads();
    }
    int prefix = tmp[0];
    int gid = b * BLOCK + threadIdx.x;
    if (gid < n) {
        off[gid] += prefix;
        dinv[gid] = rsqrtf((float)(deg_i[gid] + 1));
        cursor[gid] = 0;
    }
    if (b == 0 && threadIdx.x == 0) off[n] = E;
}

__global__ __launch_bounds__(BLOCK) void k_fill(const int* __restrict__ src,
                                                const int* __restrict__ dst, int E,
                                                const int* __restrict__ off,
                                                int* __restrict__ cursor,
                                                int* __restrict__ csr_src) {
    int i = blockIdx.x * blockDim.x + threadIdx.x;
    int stride = gridDim.x * blockDim.x;
    for (int e = i; e < E; e += stride) {
        int d = dst[e];
        int pos = atomicAdd(&cursor[d], 1);
        csr_src[off[d] + pos] = src[e];
    }
}

// ---------------- gather (bf16 rows): aggx[d] = dinv[d]*sum(dinv[s]*x[s]) + dinv[d]^2*x[d] ----------------

__global__ __launch_bounds__(BLOCK) void k_gather(const int* __restrict__ off,
                                                  const int* __restrict__ csr_src,
                                                  const float* __restrict__ dinv,
                                                  const unsigned short* __restrict__ xh,
                                                  const float* __restrict__ x,
                                                  float* __restrict__ aggx, int n) {
    int wave = (blockIdx.x * blockDim.x + threadIdx.x) >> 6;
    int lane = threadIdx.x & 63;
    if (wave >= n) return;
    int d = wave;
    int beg = off[d], end = off[d + 1];

    float accx = 0.f, accy = 0.f;
    for (int base = beg; base < end; base += 64) {
        int cnt = min(64, end - base);
        int s = 0; float w = 0.f;
        if (lane < cnt) { s = csr_src[base + lane]; w = dinv[s]; }
        int j = 0;
        for (; j + 4 <= cnt; j += 4) {
            int s0 = __shfl(s, j);
            int s1 = __shfl(s, j + 1);
            int s2 = __shfl(s, j + 2);
            int s3 = __shfl(s, j + 3);
            float w0 = __shfl(w, j);
            float w1 = __shfl(w, j + 1);
            float w2 = __shfl(w, j + 2);
            float w3 = __shfl(w, j + 3);
            ushort2 v0 = ((const ushort2*)(xh + (size_t)s0 * 128))[lane];
            ushort2 v1 = ((const ushort2*)(xh + (size_t)s1 * 128))[lane];
            ushort2 v2 = ((const ushort2*)(xh + (size_t)s2 * 128))[lane];
            ushort2 v3 = ((const ushort2*)(xh + (size_t)s3 * 128))[lane];
            accx += w0 * bf2f(v0.x) + w1 * bf2f(v1.x) + w2 * bf2f(v2.x) + w3 * bf2f(v3.x);
            accy += w0 * bf2f(v0.y) + w1 * bf2f(v1.y) + w2 * bf2f(v2.y) + w3 * bf2f(v3.y);
        }
        for (; j < cnt; j++) {
            int sj = __shfl(s, j);
            float wj = __shfl(w, j);
            ushort2 v = ((const ushort2*)(xh + (size_t)sj * 128))[lane];
            accx += wj * bf2f(v.x);
            accy += wj * bf2f(v.y);
        }
    }
    float dv = dinv[d];
    float2 xv = ((const float2*)(x + (size_t)d * 128))[lane];  // self-loop in fp32
    float2 o;
    o.x = dv * accx + dv * dv * xv.x;
    o.y = dv * accy + dv * dv * xv.y;
    ((float2*)(aggx + (size_t)d * 128))[lane] = o;
}

// ---------------- tiled GEMM: out = aggx @ Wf + bf (split high/low store) ----------------

__global__ __launch_bounds__(BLOCK) void k_final(const float* __restrict__ aggx,
                                                 const float* __restrict__ Wf,
                                                 const float* __restrict__ bf,
                                                 float* __restrict__ out, int n) {
    __shared__ float Xs[BK][BM];
    __shared__ float Ws[BK][BM];
    int rg = threadIdx.x >> 3;
    int cg = threadIdx.x & 7;
    int row0 = blockIdx.x * BM;

    float acc[4][16];
#pragma unroll
    for (int r = 0; r < 4; r++)
#pragma unroll
        for (int j = 0; j < 16; j++) acc[r][j] = 0.f;

    for (int kt = 0; kt < 128; kt += BK) {
        int kt4 = kt >> 2;
#pragma unroll
        for (int i = 0; i < 4; i++) {
            int s = threadIdx.x + i * 256;
            int r = s >> 3;
            int c4 = s & 7;
            int gr = row0 + r;
            if (gr >= n) gr = n - 1;
            float4 v = ((const float4*)(aggx + (size_t)gr * 128))[kt4 + c4];
            Xs[c4 * 4 + 0][r] = v.x;
            Xs[c4 * 4 + 1][r] = v.y;
            Xs[c4 * 4 + 2][r] = v.z;
            Xs[c4 * 4 + 3][r] = v.w;
        }
#pragma unroll
        for (int i = 0; i < 4; i++) {
            int s = threadIdx.x + i * 256;
            int k = s >> 5;
            int c4 = s & 31;
            float4 v = ((const float4*)(Wf + (size_t)(kt + k) * 128))[c4];
            *(float4*)&Ws[k][c4 * 4] = v;
        }
        __syncthreads();

#pragma unroll 4
        for (int k = 0; k < BK; k++) {
            float xf[4];
            *(float4*)xf = *(const float4*)&Xs[k][rg * 4];
            float wf[16];
            const float4* wrow = (const float4*)&Ws[k][cg * 16];
            ((float4*)wf)[0] = wrow[0];
            ((float4*)wf)[1] = wrow[1];
            ((float4*)wf)[2] = wrow[2];
            ((float4*)wf)[3] = wrow[3];
#pragma unroll
            for (int r = 0; r < 4; r++)
#pragma unroll
                for (int j = 0; j < 16; j++) acc[r][j] += xf[r] * wf[j];
        }
        __syncthreads();
    }

    float bvf[16];
#pragma unroll
    for (int j4 = 0; j4 < 4; j4++)
        ((float4*)bvf)[j4] = ((const float4*)(bf + cg * 16))[j4];

#pragma unroll
    for (int r = 0; r < 4; r++) {
        int row = row0 + rg * 4 + r;
        if (row >= n) break;
        float* base = (cg < 4) ? (out + (size_t)row * 64 + cg * 16)
                               : (out + (size_t)n * 64 + (size_t)row * 64 + (cg - 4) * 16);
#pragma unroll
        for (int j4 = 0; j4 < 4; j4++) {
            float4 v = make_float4(acc[r][j4 * 4 + 0] + bvf[j4 * 4 + 0],
                                   acc[r][j4 * 4 + 1] + bvf[j4 * 4 + 1],
                                   acc[r][j4 * 4 + 2] + bvf[j4 * 4 + 2],
                                   acc[r][j4 * 4 + 3] + bvf[j4 * 4 + 3]);
            ((float4*)base)[j4] = v;
        }
    }
}

extern "C" void kernel_launch(void* const* d_in, const int* in_sizes, int n_in,
                              void* d_out, int out_size, void* d_ws, size_t ws_size,
                              hipStream_t stream) {
    const float* x  = (const float*)d_in[0];
    const int*   ei = (const int*)d_in[1];
    const float* Wg = (const float*)d_in[2];
    const float* bg = (const float*)d_in[3];
    const float* Wh = (const float*)d_in[4];
    const float* bh = (const float*)d_in[5];
    const float* Wl = (const float*)d_in[6];
    const float* bl = (const float*)d_in[7];
    float* out = (float*)d_out;

    int n = in_sizes[0] / 128;
    int E = in_sizes[1] / 2;
    const int* src = ei;
    const int* dst = ei + E;
    int nb = (n + BLOCK - 1) / BLOCK;

    char* ws = (char*)d_ws;
    int*   deg_i  = (int*)ws;                     ws += (size_t)n * 4;
    int*   off    = (int*)ws;                     ws += (size_t)(n + 1) * 4;
    int*   cursor = (int*)ws;                     ws += (size_t)n * 4;
    int*   bsum   = (int*)ws;                     ws += (size_t)nb * 4;
    int*   csr    = (int*)ws;                     ws += (size_t)E * 4;
    float* dinv   = (float*)ws;                   ws += (size_t)n * 4;
    float* aggx   = (float*)ws;                   ws += (size_t)n * 128 * 4;
    float* Wf     = (float*)ws;                   ws += (size_t)128 * 128 * 4;
    float* bf     = (float*)ws;                   ws += (size_t)128 * 4;
    unsigned short* xh = (unsigned short*)ws;

    hipMemsetAsync(deg_i, 0, (size_t)n * sizeof(int), stream);

    k_prep<<<17 + 1024 + CONV_BLOCKS, BLOCK, 0, stream>>>(
        x, dst, E, Wg, Wh, Wl, bg, bh, bl, Wf, bf, deg_i, xh, n);
    k_scan1<<<nb, BLOCK, 0, stream>>>(deg_i, off, bsum, n);
    k_scan3x<<<nb, BLOCK, 0, stream>>>(off, bsum, deg_i, dinv, cursor, n, E);
    k_fill<<<1024, BLOCK, 0, stream>>>(src, dst, E, off, cursor, csr);
    k_gather<<<((size_t)n * 64 + BLOCK - 1) / BLOCK, BLOCK, 0, stream>>>(off, csr, dinv, xh, x, aggx, n);
    k_final<<<(n + BM - 1) / BM, BLOCK, 0, stream>>>(aggx, Wf, bf, out, n);
}

// Round 7
// 330.146 us; speedup vs baseline: 3.6897x; 1.0609x over previous
//
#include <hip/hip_runtime.h>

// GCNConv(100k nodes, 1M edges, D=128) + two heads (128->64), fp32.
// R7: single-pass CSR via fixed-capacity buckets (cap=64, Poisson lambda=10;
// overflow side-list for unconditional correctness). Deletes count pass,
// both scan kernels, and the dinv array (rsqrt on the fly).
// 4 GPU ops: memset | prep(fuse + convert + direct-fill) | gather | final.
//
// ws: cursor[n] | ovf_cnt[4] | ovf[2*4096] | slots[n*64] | aggx[n*128] f32
//     | Wf[128*128] | bf[128] | xh[n*128] bf16   (~103 MB)

#define BLOCK 256
#define BM 128
#define BK 32
#define CAP 64
#define OVF_MAX 4096
#define FILL_BLOCKS 2048
#define CONV_BLOCKS 4096

__device__ inline unsigned short f2bf(float f) {
    unsigned u = __float_as_uint(f);
    unsigned r = (u + 0x7FFF + ((u >> 16) & 1)) >> 16;  // RNE
    return (unsigned short)r;
}
__device__ inline float bf2f(unsigned short u) {
    return __uint_as_float(((unsigned)u) << 16);
}

// ---------------- prep: weight fusion | direct bucket fill | x -> bf16 ----------------

__global__ __launch_bounds__(BLOCK) void k_prep(const float* __restrict__ x,
                                                const int* __restrict__ src,
                                                const int* __restrict__ dst, int E,
                                                const float* __restrict__ Wg,
                                                const float* __restrict__ Wh,
                                                const float* __restrict__ Wl,
                                                const float* __restrict__ bg,
                                                const float* __restrict__ bh,
                                                const float* __restrict__ bl,
                                                float* __restrict__ Wf,
                                                float* __restrict__ bf,
                                                int* __restrict__ cursor,
                                                int* __restrict__ ovf_cnt,
                                                int* __restrict__ ovf,
                                                int* __restrict__ slots,
                                                unsigned short* __restrict__ xh,
                                                int n) {
    int b = blockIdx.x;
    if (b < 16) {  // Wf = Wg @ [Wh|Wl]
        int r = b * 8 + (threadIdx.x >> 5);
        int c0 = (threadIdx.x & 31) * 4;
        float a0 = 0.f, a1 = 0.f, a2 = 0.f, a3 = 0.f;
        for (int j = 0; j < 128; j++) {
            float wg = Wg[r * 128 + j];
            float4 wc;
            if (c0 < 64) wc = *(const float4*)(Wh + j * 64 + c0);
            else         wc = *(const float4*)(Wl + j * 64 + (c0 - 64));
            a0 += wg * wc.x; a1 += wg * wc.y; a2 += wg * wc.z; a3 += wg * wc.w;
        }
        *(float4*)(Wf + r * 128 + c0) = make_float4(a0, a1, a2, a3);
    } else if (b == 16) {  // bf = bg @ [Wh|Wl] + [bh|bl]
        int c = threadIdx.x;
        if (c < 128) {
            float acc = (c < 64) ? bh[c] : bl[c - 64];
            for (int j = 0; j < 128; j++) {
                float wc = (c < 64) ? Wh[j * 64 + c] : Wl[j * 64 + (c - 64)];
                acc += bg[j] * wc;
            }
            bf[c] = acc;
        }
    } else if (b < 17 + FILL_BLOCKS) {  // direct fill: one atomic pass, no scan
        int i = (b - 17) * BLOCK + threadIdx.x;
        int stride = FILL_BLOCKS * BLOCK;
        for (int e = i; e < E; e += stride) {
            int d = dst[e];
            int s = src[e];
            int pos = atomicAdd(&cursor[d], 1);
            if (pos < CAP) {
                slots[((size_t)d << 6) + pos] = s;
            } else {
                int o = atomicAdd(ovf_cnt, 1);
                if (o < OVF_MAX) { ovf[2 * o] = d; ovf[2 * o + 1] = s; }
            }
        }
    } else {  // x -> bf16
        const float4* x4 = (const float4*)x;
        ushort4* o4 = (ushort4*)xh;
        int total = n * 32;
        int i = (b - 17 - FILL_BLOCKS) * BLOCK + threadIdx.x;
        int stride = CONV_BLOCKS * BLOCK;
        for (; i < total; i += stride) {
            float4 v = x4[i];
            ushort4 o;
            o.x = f2bf(v.x); o.y = f2bf(v.y); o.z = f2bf(v.z); o.w = f2bf(v.w);
            o4[i] = o;
        }
    }
}

// ---------------- gather: aggx[d] = dv*sum(dinv[s]*x[s]) + dv^2*x[d] ----------------
// one wave per node; deg<=64 slotted (single prefetch), overflow side-scan.

__global__ __launch_bounds__(BLOCK) void k_gather(const int* __restrict__ cursor,
                                                  const int* __restrict__ slots,
                                                  const int* __restrict__ ovf_cnt,
                                                  const int* __restrict__ ovf,
                                                  const unsigned short* __restrict__ xh,
                                                  const float* __restrict__ x,
                                                  float* __restrict__ aggx, int n) {
    int wave = (blockIdx.x * blockDim.x + threadIdx.x) >> 6;
    int lane = threadIdx.x & 63;
    if (wave >= n) return;
    int d = wave;
    int deg = cursor[d];
    int cnt = min(deg, CAP);

    int s = 0; float w = 0.f;
    if (lane < cnt) {
        s = slots[((size_t)d << 6) + lane];
        w = rsqrtf((float)(cursor[s] + 1));
    }

    float accx = 0.f, accy = 0.f;
    int j = 0;
    for (; j + 4 <= cnt; j += 4) {
        int s0 = __shfl(s, j);
        int s1 = __shfl(s, j + 1);
        int s2 = __shfl(s, j + 2);
        int s3 = __shfl(s, j + 3);
        float w0 = __shfl(w, j);
        float w1 = __shfl(w, j + 1);
        float w2 = __shfl(w, j + 2);
        float w3 = __shfl(w, j + 3);
        ushort2 v0 = ((const ushort2*)(xh + (size_t)s0 * 128))[lane];
        ushort2 v1 = ((const ushort2*)(xh + (size_t)s1 * 128))[lane];
        ushort2 v2 = ((const ushort2*)(xh + (size_t)s2 * 128))[lane];
        ushort2 v3 = ((const ushort2*)(xh + (size_t)s3 * 128))[lane];
        accx += w0 * bf2f(v0.x) + w1 * bf2f(v1.x) + w2 * bf2f(v2.x) + w3 * bf2f(v3.x);
        accy += w0 * bf2f(v0.y) + w1 * bf2f(v1.y) + w2 * bf2f(v2.y) + w3 * bf2f(v3.y);
    }
    for (; j < cnt; j++) {
        int sj = __shfl(s, j);
        float wj = __shfl(w, j);
        ushort2 v = ((const ushort2*)(xh + (size_t)sj * 128))[lane];
        accx += wj * bf2f(v.x);
        accy += wj * bf2f(v.y);
    }

    // overflow side-list (normally empty): every wave scans it
    int n_o = min(*ovf_cnt, OVF_MAX);
    for (int i = 0; i < n_o; i++) {
        if (ovf[2 * i] == d) {
            int so = ovf[2 * i + 1];
            float wo = rsqrtf((float)(cursor[so] + 1));
            ushort2 v = ((const ushort2*)(xh + (size_t)so * 128))[lane];
            accx += wo * bf2f(v.x);
            accy += wo * bf2f(v.y);
        }
    }

    float dv = rsqrtf((float)(deg + 1));
    float2 xv = ((const float2*)(x + (size_t)d * 128))[lane];  // self-loop fp32
    float2 o;
    o.x = dv * accx + dv * dv * xv.x;
    o.y = dv * accy + dv * dv * xv.y;
    ((float2*)(aggx + (size_t)d * 128))[lane] = o;
}

// ---------------- tiled GEMM: out = aggx @ Wf + bf (split high/low store) ----------------

__global__ __launch_bounds__(BLOCK) void k_final(const float* __restrict__ aggx,
                                                 const float* __restrict__ Wf,
                                                 const float* __restrict__ bf,
                                                 float* __restrict__ out, int n) {
    __shared__ float Xs[BK][BM];
    __shared__ float Ws[BK][BM];
    int rg = threadIdx.x >> 3;
    int cg = threadIdx.x & 7;
    int row0 = blockIdx.x * BM;

    float acc[4][16];
#pragma unroll
    for (int r = 0; r < 4; r++)
#pragma unroll
        for (int j = 0; j < 16; j++) acc[r][j] = 0.f;

    for (int kt = 0; kt < 128; kt += BK) {
        int kt4 = kt >> 2;
#pragma unroll
        for (int i = 0; i < 4; i++) {
            int s = threadIdx.x + i * 256;
            int r = s >> 3;
            int c4 = s & 7;
            int gr = row0 + r;
            if (gr >= n) gr = n - 1;
            float4 v = ((const float4*)(aggx + (size_t)gr * 128))[kt4 + c4];
            Xs[c4 * 4 + 0][r] = v.x;
            Xs[c4 * 4 + 1][r] = v.y;
            Xs[c4 * 4 + 2][r] = v.z;
            Xs[c4 * 4 + 3][r] = v.w;
        }
#pragma unroll
        for (int i = 0; i < 4; i++) {
            int s = threadIdx.x + i * 256;
            int k = s >> 5;
            int c4 = s & 31;
            float4 v = ((const float4*)(Wf + (size_t)(kt + k) * 128))[c4];
            *(float4*)&Ws[k][c4 * 4] = v;
        }
        __syncthreads();

#pragma unroll 4
        for (int k = 0; k < BK; k++) {
            float xf[4];
            *(float4*)xf = *(const float4*)&Xs[k][rg * 4];
            float wf[16];
            const float4* wrow = (const float4*)&Ws[k][cg * 16];
            ((float4*)wf)[0] = wrow[0];
            ((float4*)wf)[1] = wrow[1];
            ((float4*)wf)[2] = wrow[2];
            ((float4*)wf)[3] = wrow[3];
#pragma unroll
            for (int r = 0; r < 4; r++)
#pragma unroll
                for (int j = 0; j < 16; j++) acc[r][j] += xf[r] * wf[j];
        }
        __syncthreads();
    }

    float bvf[16];
#pragma unroll
    for (int j4 = 0; j4 < 4; j4++)
        ((float4*)bvf)[j4] = ((const float4*)(bf + cg * 16))[j4];

#pragma unroll
    for (int r = 0; r < 4; r++) {
        int row = row0 + rg * 4 + r;
        if (row >= n) break;
        float* base = (cg < 4) ? (out + (size_t)row * 64 + cg * 16)
                               : (out + (size_t)n * 64 + (size_t)row * 64 + (cg - 4) * 16);
#pragma unroll
        for (int j4 = 0; j4 < 4; j4++) {
            float4 v = make_float4(acc[r][j4 * 4 + 0] + bvf[j4 * 4 + 0],
                                   acc[r][j4 * 4 + 1] + bvf[j4 * 4 + 1],
                                   acc[r][j4 * 4 + 2] + bvf[j4 * 4 + 2],
                                   acc[r][j4 * 4 + 3] + bvf[j4 * 4 + 3]);
            ((float4*)base)[j4] = v;
        }
    }
}

extern "C" void kernel_launch(void* const* d_in, const int* in_sizes, int n_in,
                              void* d_out, int out_size, void* d_ws, size_t ws_size,
                              hipStream_t stream) {
    const float* x  = (const float*)d_in[0];
    const int*   ei = (const int*)d_in[1];
    const float* Wg = (const float*)d_in[2];
    const float* bg = (const float*)d_in[3];
    const float* Wh = (const float*)d_in[4];
    const float* bh = (const float*)d_in[5];
    const float* Wl = (const float*)d_in[6];
    const float* bl = (const float*)d_in[7];
    float* out = (float*)d_out;

    int n = in_sizes[0] / 128;
    int E = in_sizes[1] / 2;
    const int* src = ei;
    const int* dst = ei + E;

    char* ws = (char*)d_ws;
    int*   cursor  = (int*)ws;                    ws += (size_t)n * 4;
    int*   ovf_cnt = (int*)ws;                    ws += 16;
    int*   ovf     = (int*)ws;                    ws += (size_t)2 * OVF_MAX * 4;
    int*   slots   = (int*)ws;                    ws += (size_t)n * CAP * 4;
    float* aggx    = (float*)ws;                  ws += (size_t)n * 128 * 4;
    float* Wf      = (float*)ws;                  ws += (size_t)128 * 128 * 4;
    float* bf      = (float*)ws;                  ws += (size_t)128 * 4;
    unsigned short* xh = (unsigned short*)ws;

    hipMemsetAsync(cursor, 0, (size_t)n * 4 + 16, stream);  // cursor + ovf_cnt

    k_prep<<<17 + FILL_BLOCKS + CONV_BLOCKS, BLOCK, 0, stream>>>(
        x, src, dst, E, Wg, Wh, Wl, bg, bh, bl, Wf, bf,
        cursor, ovf_cnt, ovf, slots, xh, n);
    k_gather<<<((size_t)n * 64 + BLOCK - 1) / BLOCK, BLOCK, 0, stream>>>(
        cursor, slots, ovf_cnt, ovf, xh, x, aggx, n);
    k_final<<<(n + BM - 1) / BM, BLOCK, 0, stream>>>(aggx, Wf, bf, out, n);
}

// Round 8
// 294.441 us; speedup vs baseline: 4.1371x; 1.1213x over previous
//
#include <hip/hip_runtime.h>

// GCNConv(100k nodes, 1M edges, D=128) + two heads (128->64), fp32.
// R8: atomic-free CSR via two-level counting sort (coarse bucket = dst>>7,
// LDS histograms + LDS cursors only; plain stores, no global RMW).
// Pipeline: prep(fuse|convert|countA) -> scanA -> scanB -> scatter -> node
//           -> gather(bf16) -> final GEMM.  No memsets.
//
// ws: hist_g[NB*512] | bucketTotal[NB] | bucketStart[NB+1] | ebuf[E] int2
//     | off[n+1] | dinv[n] | csr[E] | aggx[n*128] f32 | Wf | bf | xh bf16

#define BLOCK 256
#define BM 128
#define BK 32
#define SB 512          // scatter blocks (pass A/C)
#define NB_MAX 784      // max coarse buckets (n<=100352)
#define CONV_BLOCKS 4096

__device__ inline unsigned short f2bf(float f) {
    unsigned u = __float_as_uint(f);
    unsigned r = (u + 0x7FFF + ((u >> 16) & 1)) >> 16;  // RNE
    return (unsigned short)r;
}
__device__ inline float bf2f(unsigned short u) {
    return __uint_as_float(((unsigned)u) << 16);
}

// ---------------- prep: weight fusion | x->bf16 | pass A (bucket count) ----------------

__global__ __launch_bounds__(BLOCK) void k_prep(const float* __restrict__ x,
                                                const int* __restrict__ dst, int E,
                                                const float* __restrict__ Wg,
                                                const float* __restrict__ Wh,
                                                const float* __restrict__ Wl,
                                                const float* __restrict__ bg,
                                                const float* __restrict__ bh,
                                                const float* __restrict__ bl,
                                                float* __restrict__ Wf,
                                                float* __restrict__ bf,
                                                int* __restrict__ hist_g,
                                                unsigned short* __restrict__ xh,
                                                int n, int NB) {
    __shared__ int hist[NB_MAX];
    int b = blockIdx.x;
    if (b < 16) {  // Wf = Wg @ [Wh|Wl]
        int r = b * 8 + (threadIdx.x >> 5);
        int c0 = (threadIdx.x & 31) * 4;
        float a0 = 0.f, a1 = 0.f, a2 = 0.f, a3 = 0.f;
        for (int j = 0; j < 128; j++) {
            float wg = Wg[r * 128 + j];
            float4 wc;
            if (c0 < 64) wc = *(const float4*)(Wh + j * 64 + c0);
            else         wc = *(const float4*)(Wl + j * 64 + (c0 - 64));
            a0 += wg * wc.x; a1 += wg * wc.y; a2 += wg * wc.z; a3 += wg * wc.w;
        }
        *(float4*)(Wf + r * 128 + c0) = make_float4(a0, a1, a2, a3);
    } else if (b == 16) {  // bf = bg @ [Wh|Wl] + [bh|bl]
        int c = threadIdx.x;
        if (c < 128) {
            float acc = (c < 64) ? bh[c] : bl[c - 64];
            for (int j = 0; j < 128; j++) {
                float wc = (c < 64) ? Wh[j * 64 + c] : Wl[j * 64 + (c - 64)];
                acc += bg[j] * wc;
            }
            bf[c] = acc;
        }
    } else if (b < 17 + SB) {  // pass A: LDS bucket histogram of this block's chunk
        int blk = b - 17;
        for (int i = threadIdx.x; i < NB; i += BLOCK) hist[i] = 0;
        __syncthreads();
        int chunk = (E + SB - 1) / SB;
        int e0 = blk * chunk, e1 = min(E, e0 + chunk);
        for (int e = e0 + threadIdx.x; e < e1; e += BLOCK)
            atomicAdd(&hist[dst[e] >> 7], 1);
        __syncthreads();
        for (int i = threadIdx.x; i < NB; i += BLOCK)
            hist_g[(size_t)i * SB + blk] = hist[i];
    } else {  // x -> bf16
        const float4* x4 = (const float4*)x;
        ushort4* o4 = (ushort4*)xh;
        int total = n * 32;
        int i = (b - 17 - SB) * BLOCK + threadIdx.x;
        int stride = CONV_BLOCKS * BLOCK;
        for (; i < total; i += stride) {
            float4 v = x4[i];
            ushort4 o;
            o.x = f2bf(v.x); o.y = f2bf(v.y); o.z = f2bf(v.z); o.w = f2bf(v.w);
            o4[i] = o;
        }
    }
}

// ---------------- scan A: per-bucket exclusive prefix over SB blocks ----------------

__global__ __launch_bounds__(BLOCK) void k_scanA(int* __restrict__ hist_g,
                                                 int* __restrict__ bucketTotal, int NB) {
    __shared__ int s[SB];
    int bkt = blockIdx.x;
    int t = threadIdx.x;
    int a0 = hist_g[(size_t)bkt * SB + t];
    int a1 = hist_g[(size_t)bkt * SB + t + 256];
    s[t] = a0; s[t + 256] = a1;
    __syncthreads();
    for (int ofs = 1; ofs < SB; ofs <<= 1) {
        int v0 = (t >= ofs) ? s[t - ofs] : 0;
        int v1 = (t + 256 >= ofs) ? s[t + 256 - ofs] : 0;
        __syncthreads();
        s[t] += v0; s[t + 256] += v1;
        __syncthreads();
    }
    hist_g[(size_t)bkt * SB + t] = s[t] - a0;              // exclusive
    hist_g[(size_t)bkt * SB + t + 256] = s[t + 256] - a1;
    if (t == 255) bucketTotal[bkt] = s[SB - 1];
}

// ---------------- scan B: exclusive scan over buckets ----------------

__global__ __launch_bounds__(1024) void k_scanB(const int* __restrict__ bucketTotal,
                                                int* __restrict__ bucketStart,
                                                int NB, int E) {
    __shared__ int s[1024];
    int t = threadIdx.x;
    int v = (t < NB) ? bucketTotal[t] : 0;
    s[t] = v;
    __syncthreads();
    for (int ofs = 1; ofs < 1024; ofs <<= 1) {
        int u = (t >= ofs) ? s[t - ofs] : 0;
        __syncthreads();
        s[t] += u;
        __syncthreads();
    }
    if (t < NB) bucketStart[t] = s[t] - v;
    if (t == NB - 1) bucketStart[NB] = E;
}

// ---------------- pass C: scatter edges into bucket-grouped ebuf ----------------

__global__ __launch_bounds__(BLOCK) void k_scatter(const int* __restrict__ src,
                                                   const int* __restrict__ dst, int E,
                                                   const int* __restrict__ hist_g,
                                                   const int* __restrict__ bucketStart,
                                                   int2* __restrict__ ebuf, int NB) {
    __shared__ int cur[NB_MAX];
    int blk = blockIdx.x;
    for (int i = threadIdx.x; i < NB; i += BLOCK)
        cur[i] = bucketStart[i] + hist_g[(size_t)i * SB + blk];
    __syncthreads();
    int chunk = (E + SB - 1) / SB;
    int e0 = blk * chunk, e1 = min(E, e0 + chunk);
    for (int e = e0 + threadIdx.x; e < e1; e += BLOCK) {
        int d = dst[e];
        int pos = atomicAdd(&cur[d >> 7], 1);  // LDS atomic
        ebuf[pos] = make_int2(d, src[e]);
    }
}

// ---------------- pass D: per-bucket fine sort -> compact CSR + dinv ----------------

__global__ __launch_bounds__(BLOCK) void k_node(const int2* __restrict__ ebuf,
                                                const int* __restrict__ bucketStart,
                                                int* __restrict__ off,
                                                float* __restrict__ dinv,
                                                int* __restrict__ csr,
                                                int n, int NB, int E) {
    __shared__ int cnt[128];
    __shared__ int pre[128];
    __shared__ int cur[128];
    int bkt = blockIdx.x;
    int t = threadIdx.x;
    int node0 = bkt << 7;
    int nn = min(128, n - node0);
    int eb0 = bucketStart[bkt], eb1 = bucketStart[bkt + 1];

    if (t < 128) cnt[t] = 0;
    __syncthreads();
    for (int e = eb0 + t; e < eb1; e += BLOCK)
        atomicAdd(&cnt[ebuf[e].x & 127], 1);
    __syncthreads();
    if (t < 128) pre[t] = cnt[t];
    __syncthreads();
    for (int ofs = 1; ofs < 128; ofs <<= 1) {
        int v = (t < 128 && t >= ofs) ? pre[t - ofs] : 0;
        __syncthreads();
        if (t < 128) pre[t] += v;
        __syncthreads();
    }
    // pre = inclusive; exclusive = pre - cnt
    if (t < 128) cur[t] = pre[t] - cnt[t];
    __syncthreads();
    if (t < nn) {
        off[node0 + t] = eb0 + cur[t];
        dinv[node0 + t] = rsqrtf((float)(cnt[t] + 1));
    }
    if (bkt == 0 && t == 0) off[n] = E;
    for (int e = eb0 + t; e < eb1; e += BLOCK) {
        int2 p = ebuf[e];
        int pos = atomicAdd(&cur[p.x & 127], 1);  // LDS atomic
        csr[eb0 + pos] = p.y;
    }
}

// ---------------- gather: aggx[d] = dv*sum(dinv[s]*x[s]) + dv^2*x[d] ----------------

__global__ __launch_bounds__(BLOCK) void k_gather(const int* __restrict__ off,
                                                  const int* __restrict__ csr,
                                                  const float* __restrict__ dinv,
                                                  const unsigned short* __restrict__ xh,
                                                  const float* __restrict__ x,
                                                  float* __restrict__ aggx, int n) {
    int wave = (blockIdx.x * blockDim.x + threadIdx.x) >> 6;
    int lane = threadIdx.x & 63;
    if (wave >= n) return;
    int d = wave;
    int beg = off[d], end = off[d + 1];

    float accx = 0.f, accy = 0.f;
    for (int base = beg; base < end; base += 64) {
        int cnt = min(64, end - base);
        int s = 0; float w = 0.f;
        if (lane < cnt) { s = csr[base + lane]; w = dinv[s]; }
        int j = 0;
        for (; j + 4 <= cnt; j += 4) {
            int s0 = __shfl(s, j);
            int s1 = __shfl(s, j + 1);
            int s2 = __shfl(s, j + 2);
            int s3 = __shfl(s, j + 3);
            float w0 = __shfl(w, j);
            float w1 = __shfl(w, j + 1);
            float w2 = __shfl(w, j + 2);
            float w3 = __shfl(w, j + 3);
            ushort2 v0 = ((const ushort2*)(xh + (size_t)s0 * 128))[lane];
            ushort2 v1 = ((const ushort2*)(xh + (size_t)s1 * 128))[lane];
            ushort2 v2 = ((const ushort2*)(xh + (size_t)s2 * 128))[lane];
            ushort2 v3 = ((const ushort2*)(xh + (size_t)s3 * 128))[lane];
            accx += w0 * bf2f(v0.x) + w1 * bf2f(v1.x) + w2 * bf2f(v2.x) + w3 * bf2f(v3.x);
            accy += w0 * bf2f(v0.y) + w1 * bf2f(v1.y) + w2 * bf2f(v2.y) + w3 * bf2f(v3.y);
        }
        for (; j < cnt; j++) {
            int sj = __shfl(s, j);
            float wj = __shfl(w, j);
            ushort2 v = ((const ushort2*)(xh + (size_t)sj * 128))[lane];
            accx += wj * bf2f(v.x);
            accy += wj * bf2f(v.y);
        }
    }
    float dv = dinv[d];
    float2 xv = ((const float2*)(x + (size_t)d * 128))[lane];  // self-loop fp32
    float2 o;
    o.x = dv * accx + dv * dv * xv.x;
    o.y = dv * accy + dv * dv * xv.y;
    ((float2*)(aggx + (size_t)d * 128))[lane] = o;
}

// ---------------- tiled GEMM: out = aggx @ Wf + bf (split high/low store) ----------------

__global__ __launch_bounds__(BLOCK) void k_final(const float* __restrict__ aggx,
                                                 const float* __restrict__ Wf,
                                                 const float* __restrict__ bf,
                                                 float* __restrict__ out, int n) {
    __shared__ float Xs[BK][BM];
    __shared__ float Ws[BK][BM];
    int rg = threadIdx.x >> 3;
    int cg = threadIdx.x & 7;
    int row0 = blockIdx.x * BM;

    float acc[4][16];
#pragma unroll
    for (int r = 0; r < 4; r++)
#pragma unroll
        for (int j = 0; j < 16; j++) acc[r][j] = 0.f;

    for (int kt = 0; kt < 128; kt += BK) {
        int kt4 = kt >> 2;
#pragma unroll
        for (int i = 0; i < 4; i++) {
            int s = threadIdx.x + i * 256;
            int r = s >> 3;
            int c4 = s & 7;
            int gr = row0 + r;
            if (gr >= n) gr = n - 1;
            float4 v = ((const float4*)(aggx + (size_t)gr * 128))[kt4 + c4];
            Xs[c4 * 4 + 0][r] = v.x;
            Xs[c4 * 4 + 1][r] = v.y;
            Xs[c4 * 4 + 2][r] = v.z;
            Xs[c4 * 4 + 3][r] = v.w;
        }
#pragma unroll
        for (int i = 0; i < 4; i++) {
            int s = threadIdx.x + i * 256;
            int k = s >> 5;
            int c4 = s & 31;
            float4 v = ((const float4*)(Wf + (size_t)(kt + k) * 128))[c4];
            *(float4*)&Ws[k][c4 * 4] = v;
        }
        __syncthreads();

#pragma unroll 4
        for (int k = 0; k < BK; k++) {
            float xf[4];
            *(float4*)xf = *(const float4*)&Xs[k][rg * 4];
            float wf[16];
            const float4* wrow = (const float4*)&Ws[k][cg * 16];
            ((float4*)wf)[0] = wrow[0];
            ((float4*)wf)[1] = wrow[1];
            ((float4*)wf)[2] = wrow[2];
            ((float4*)wf)[3] = wrow[3];
#pragma unroll
            for (int r = 0; r < 4; r++)
#pragma unroll
                for (int j = 0; j < 16; j++) acc[r][j] += xf[r] * wf[j];
        }
        __syncthreads();
    }

    float bvf[16];
#pragma unroll
    for (int j4 = 0; j4 < 4; j4++)
        ((float4*)bvf)[j4] = ((const float4*)(bf + cg * 16))[j4];

#pragma unroll
    for (int r = 0; r < 4; r++) {
        int row = row0 + rg * 4 + r;
        if (row >= n) break;
        float* base = (cg < 4) ? (out + (size_t)row * 64 + cg * 16)
                               : (out + (size_t)n * 64 + (size_t)row * 64 + (cg - 4) * 16);
#pragma unroll
        for (int j4 = 0; j4 < 4; j4++) {
            float4 v = make_float4(acc[r][j4 * 4 + 0] + bvf[j4 * 4 + 0],
                                   acc[r][j4 * 4 + 1] + bvf[j4 * 4 + 1],
                                   acc[r][j4 * 4 + 2] + bvf[j4 * 4 + 2],
                                   acc[r][j4 * 4 + 3] + bvf[j4 * 4 + 3]);
            ((float4*)base)[j4] = v;
        }
    }
}

extern "C" void kernel_launch(void* const* d_in, const int* in_sizes, int n_in,
                              void* d_out, int out_size, void* d_ws, size_t ws_size,
                              hipStream_t stream) {
    const float* x  = (const float*)d_in[0];
    const int*   ei = (const int*)d_in[1];
    const float* Wg = (const float*)d_in[2];
    const float* bg = (const float*)d_in[3];
    const float* Wh = (const float*)d_in[4];
    const float* bh = (const float*)d_in[5];
    const float* Wl = (const float*)d_in[6];
    const float* bl = (const float*)d_in[7];
    float* out = (float*)d_out;

    int n = in_sizes[0] / 128;
    int E = in_sizes[1] / 2;
    const int* src = ei;
    const int* dst = ei + E;
    int NB = (n + 127) >> 7;

    char* ws = (char*)d_ws;
    int*   hist_g      = (int*)ws;                ws += (size_t)NB_MAX * SB * 4;
    int*   bucketTotal = (int*)ws;                ws += (size_t)NB_MAX * 4;
    int*   bucketStart = (int*)ws;                ws += (size_t)(NB_MAX + 1) * 4;
    int2*  ebuf        = (int2*)ws;               ws += (size_t)E * 8;
    int*   off         = (int*)ws;                ws += (size_t)(n + 1) * 4;
    float* dinv        = (float*)ws;              ws += (size_t)n * 4;
    int*   csr         = (int*)ws;                ws += (size_t)E * 4;
    float* aggx        = (float*)ws;              ws += (size_t)n * 128 * 4;
    float* Wf          = (float*)ws;              ws += (size_t)128 * 128 * 4;
    float* bf          = (float*)ws;              ws += (size_t)128 * 4;
    unsigned short* xh = (unsigned short*)ws;

    k_prep<<<17 + SB + CONV_BLOCKS, BLOCK, 0, stream>>>(
        x, dst, E, Wg, Wh, Wl, bg, bh, bl, Wf, bf, hist_g, xh, n, NB);
    k_scanA<<<NB, BLOCK, 0, stream>>>(hist_g, bucketTotal, NB);
    k_scanB<<<1, 1024, 0, stream>>>(bucketTotal, bucketStart, NB, E);
    k_scatter<<<SB, BLOCK, 0, stream>>>(src, dst, E, hist_g, bucketStart, ebuf, NB);
    k_node<<<NB, BLOCK, 0, stream>>>(ebuf, bucketStart, off, dinv, csr, n, NB, E);
    k_gather<<<((size_t)n * 64 + BLOCK - 1) / BLOCK, BLOCK, 0, stream>>>(
        off, csr, dinv, xh, x, aggx, n);
    k_final<<<(n + BM - 1) / BM, BLOCK, 0, stream>>>(aggx, Wf, bf, out, n);
}